// Round 6
// baseline (342.003 us; speedup 1.0000x reference)
//
#include <hip/hip_runtime.h>
#include <hip/hip_bf16.h>
#include <stdint.h>

typedef __bf16 bf16;
typedef __bf16 bf16x4 __attribute__((ext_vector_type(4)));
typedef __bf16 bf16x8 __attribute__((ext_vector_type(8)));
typedef float floatx4 __attribute__((ext_vector_type(4)));

#define B_SEQ 16
#define NLBL  5000
#define DLAT  1024
#define PDIM  1100
#define NROWS (B_SEQ * NLBL)   // 80000

// NOTE (R6): never use the builtin's immediate-offset arg — it mis-addresses.
// NOTE (R8): 32x32 MFMA frag reads 4-way bank-conflict under this LDS layout.
// NOTE (R11 FAILED): clumped 16-stage ph4 + wrong vmcnt count. NOT evidence
// against counted-vmcnt itself (R15 does it with per-phase spread + proof).
// NOTE (R12 FAILED): in-loop A=relu(hl+hpb) generation serialized ahead of
// MFMA. Keep A staging on the gload_lds DMA path.
// NOTE (R13 FAILED): frag-read-ahead within the drain-to-0 schedule is null
// by construction (lgkm retires at the next barrier anyway).
// NOTE (R14 NULL): ks-outer == ks-inner (177us both). MFMA dep chains are
// not the cost. Kept (free).
__device__ __forceinline__ void gload_lds16(const bf16* g, bf16* l) {
    __builtin_amdgcn_global_load_lds(
        (const __attribute__((address_space(1))) void*)g,
        (__attribute__((address_space(3))) void*)l, 16, 0, 0);
}

__device__ __forceinline__ bf16x8 cvt8(const float* s) {
    floatx4 a = *(const floatx4*)s;
    floatx4 b = *(const floatx4*)(s + 4);
    bf16x8 o;
    o[0] = (bf16)a.x; o[1] = (bf16)a.y; o[2] = (bf16)a.z; o[3] = (bf16)a.w;
    o[4] = (bf16)b.x; o[5] = (bf16)b.y; o[6] = (bf16)b.z; o[7] = (bf16)b.w;
    return o;
}

__device__ __forceinline__ void barx() {
    asm volatile("" ::: "memory");
    __builtin_amdgcn_s_barrier();
    asm volatile("" ::: "memory");
}

// ============ K1: prep ============
#define PSEG_M    256
#define PSEG_LAB  2756
#define PSEG_W2   3268
#define PSEG_PE   3524
#define PSEG_END  3837

__global__ __launch_bounds__(256)
void prep_kernel(const float* __restrict__ label, bf16* __restrict__ label_b,
                 const float* __restrict__ W2, bf16* __restrict__ W2_b,
                 const float* __restrict__ W1, const float* __restrict__ Wl,
                 bf16* __restrict__ M_bf,
                 const float* __restrict__ seq, const float* __restrict__ Wp,
                 float* __restrict__ Pe,
                 float* __restrict__ out, const float* __restrict__ b3) {
    __shared__ bf16 MAs[64 * 72];
    __shared__ bf16 MBs[64 * 72];
    const int blk = blockIdx.x;
    const int t = threadIdx.x;

    if (blk < PSEG_M) {                     // M-product, 64x64 tiles, 16x16 grid
        const int m0 = (blk >> 4) * 64;
        const int n0g = (blk & 15) * 64;
        const int wave = t >> 6, lane = t & 63;
        const int wm = (wave & 1) * 32, wn = (wave >> 1) * 32;
        const int lm = lane & 15, quad = lane >> 4;
        const int a_r = t >> 2, a_c = (t & 3) * 16;
        const int b_kr = t >> 4, b_l = (t & 15) * 4;
        floatx4 acc[2][2] = {};

        for (int k0 = 0; k0 < 1024; k0 += 64) {
            const float* ap = W1 + (size_t)(m0 + a_r) * 2048 + 1024 + k0 + a_c;
            *(bf16x8*)(MAs + a_r * 72 + a_c) = cvt8(ap);
            *(bf16x8*)(MAs + a_r * 72 + a_c + 8) = cvt8(ap + 8);
#pragma unroll
            for (int ps = 0; ps < 4; ++ps) {
                int kr = b_kr + ps * 16;
                floatx4 v = *(const floatx4*)(Wl + (size_t)(k0 + kr) * 1024 + n0g + b_l);
                MBs[(b_l + 0) * 72 + kr] = (bf16)v.x;
                MBs[(b_l + 1) * 72 + kr] = (bf16)v.y;
                MBs[(b_l + 2) * 72 + kr] = (bf16)v.z;
                MBs[(b_l + 3) * 72 + kr] = (bf16)v.w;
            }
            __syncthreads();
#pragma unroll
            for (int ks = 0; ks < 2; ++ks) {
                bf16x8 af[2], bg[2];
#pragma unroll
                for (int mi = 0; mi < 2; ++mi)
                    af[mi] = *(const bf16x8*)(MAs + (wm + mi * 16 + lm) * 72 + ks * 32 + quad * 8);
#pragma unroll
                for (int ni = 0; ni < 2; ++ni)
                    bg[ni] = *(const bf16x8*)(MBs + (wn + ni * 16 + lm) * 72 + ks * 32 + quad * 8);
#pragma unroll
                for (int mi = 0; mi < 2; ++mi)
#pragma unroll
                    for (int ni = 0; ni < 2; ++ni)
                        acc[mi][ni] = __builtin_amdgcn_mfma_f32_16x16x32_bf16(af[mi], bg[ni], acc[mi][ni], 0, 0, 0);
            }
            __syncthreads();
        }
#pragma unroll
        for (int mi = 0; mi < 2; ++mi)
#pragma unroll
            for (int r = 0; r < 4; ++r)
#pragma unroll
                for (int ni = 0; ni < 2; ++ni)
                    M_bf[(size_t)(m0 + wm + mi * 16 + quad * 4 + r) * 1024 + n0g + wn + ni * 16 + lm] =
                        (bf16)acc[mi][ni][r];
    } else if (blk < PSEG_LAB) {            // label convert
        int i = (blk - PSEG_M) * 256 + t;
        ((bf16x8*)label_b)[i] = cvt8(label + (size_t)i * 8);
    } else if (blk < PSEG_W2) {             // W2 convert
        int i = (blk - PSEG_LAB) * 256 + t;
        ((bf16x8*)W2_b)[i] = cvt8(W2 + (size_t)i * 8);
    } else if (blk < PSEG_PE) {             // Pe, wave per d
        int w = (blk - PSEG_W2) * 4 + (t >> 6);
        int l = t & 63;
        floatx4 wv[5];
#pragma unroll
        for (int k = 0; k < 5; ++k) {
            int g = l + 64 * k;
            wv[k] = (g < 275) ? *(const floatx4*)(Wp + (size_t)w * PDIM + g * 4)
                              : floatx4{0.f, 0.f, 0.f, 0.f};
        }
        for (int b = 0; b < B_SEQ; ++b) {
            float acc = 0.f;
#pragma unroll
            for (int k = 0; k < 5; ++k) {
                int g = l + 64 * k;
                if (g < 275) {
                    floatx4 sv = *(const floatx4*)(seq + (size_t)b * PDIM + g * 4);
                    acc += wv[k].x * sv.x + wv[k].y * sv.y + wv[k].z * sv.z + wv[k].w * sv.w;
                }
            }
#pragma unroll
            for (int off = 32; off; off >>= 1) acc += __shfl_xor(acc, off, 64);
            if (l == 0) Pe[b * DLAT + w] = acc;
        }
    } else {                                // out init
        int i = (blk - PSEG_PE) * 256 + t;
        if (i < NROWS) out[i] = b3[0];
    }
}

// ============ K2: hpb[b,o] = b1[o] + Pe[b,:].W1[o,0:1024]  (f32 exact) ============

__global__ __launch_bounds__(256)
void hpb_kernel(const float* __restrict__ Pe, const float* __restrict__ W1,
                const float* __restrict__ b1, float* __restrict__ hpb) {
    int w = blockIdx.x * 4 + (threadIdx.x >> 6);
    int l = threadIdx.x & 63;
    floatx4 wv[4];
#pragma unroll
    for (int k = 0; k < 4; ++k)
        wv[k] = *(const floatx4*)(W1 + (size_t)w * 2048 + (l + 64 * k) * 4);
    for (int b = 0; b < B_SEQ; ++b) {
        float acc = 0.f;
#pragma unroll
        for (int k = 0; k < 4; ++k) {
            floatx4 pv = *(const floatx4*)(Pe + (size_t)b * DLAT + (l + 64 * k) * 4);
            acc += wv[k].x * pv.x + wv[k].y * pv.y + wv[k].z * pv.z + wv[k].w * pv.w;
        }
#pragma unroll
        for (int off = 32; off; off >>= 1) acc += __shfl_xor(acc, off, 64);
        if (l == 0) hpb[b * DLAT + w] = acc + b1[w];
    }
}

// ============ K3: hl GEMM (label @ M.T) with coalesced h1 epilogue ============

__global__ __launch_bounds__(256)
void hl_h1_kernel(const bf16* __restrict__ A, const bf16* __restrict__ Bt,
                  const float* __restrict__ hpb, bf16* __restrict__ h1) {
    __shared__ __align__(16) char smem[25600];
    bf16* As = (bf16*)smem;                 // 64 x 64 = 8 KB (K-loop)
    bf16* Bs = (bf16*)(smem + 8192);        // 128 x 64 = 16 KB (K-loop)
    bf16* Ls = (bf16*)smem;                 // 64*136*2 = 17408 B (epilogue)
    float* hpbs = (float*)(smem + 17408);   // 16*128*4 = 8192 B (epilogue)

    const int t = threadIdx.x;
    const int d0 = blockIdx.x * 128;        // d-tile (8)
    const int n0 = blockIdx.y * 64;         // n-tile (79, last partial)
    const int wave = t >> 6, lane = t & 63;
    const int wm = (wave & 1) * 32;         // n offset within 64
    const int wn = (wave >> 1) * 64;        // d offset within 128
    const int lm = lane & 15, quad = lane >> 4;
    const int sw = lm & 7;
    const int srow = t >> 3;                // 0..31
    const int scg0 = t & 7;
    const int sbase = (t & 192) * 8;

    floatx4 acc[2][4] = {};

    for (int k0 = 0; k0 < 1024; k0 += 64) {
#pragma unroll
        for (int p = 0; p < 2; ++p) {       // A: 64 label rows
            int row = p * 32 + srow;
            int cg = scg0 ^ (row & 7);
            int grow = n0 + row; if (grow >= NLBL) grow = NLBL - 1;
            gload_lds16(A + (size_t)grow * 1024 + k0 + cg * 8, As + p * 2048 + sbase);
        }
#pragma unroll
        for (int p = 0; p < 4; ++p) {       // B: 128 M_bf rows (d)
            int row = p * 32 + srow;
            int cg = scg0 ^ (row & 7);
            gload_lds16(Bt + (size_t)(d0 + row) * 1024 + k0 + cg * 8, Bs + p * 2048 + sbase);
        }
        __syncthreads();
#pragma unroll
        for (int k = 0; k < 64; k += 32) {
            bf16x8 af[2], bg[4];
            int ko = (((k >> 3) + quad) ^ sw) * 8;
#pragma unroll
            for (int mi = 0; mi < 2; ++mi)
                af[mi] = *(const bf16x8*)(As + (wm + mi * 16 + lm) * 64 + ko);
#pragma unroll
            for (int ni = 0; ni < 4; ++ni)
                bg[ni] = *(const bf16x8*)(Bs + (wn + ni * 16 + lm) * 64 + ko);
#pragma unroll
            for (int mi = 0; mi < 2; ++mi)
#pragma unroll
                for (int ni = 0; ni < 4; ++ni)
                    acc[mi][ni] = __builtin_amdgcn_mfma_f32_16x16x32_bf16(af[mi], bg[ni], acc[mi][ni], 0, 0, 0);
        }
        __syncthreads();
    }

    // acc -> Ls (bf16 hl tile), stage hpb slice
#pragma unroll
    for (int mi = 0; mi < 2; ++mi)
#pragma unroll
        for (int r = 0; r < 4; ++r)
#pragma unroll
            for (int ni = 0; ni < 4; ++ni)
                Ls[(wm + mi * 16 + quad * 4 + r) * 136 + wn + ni * 16 + lm] =
                    (bf16)acc[mi][ni][r];
    {
        int dl = (t & 31) * 4;
        int b = t >> 5;                     // 0..7
        *(floatx4*)(hpbs + b * 128 + dl) =
            *(const floatx4*)(hpb + (size_t)b * DLAT + d0 + dl);
        *(floatx4*)(hpbs + (b + 8) * 128 + dl) =
            *(const floatx4*)(hpb + (size_t)(b + 8) * DLAT + d0 + dl);
    }
    __syncthreads();

    const int g = t & 15;                   // d-granule (16B)
    const int r0 = t >> 4;                  // 0..15 base row
    bf16x8 hlv[4];
#pragma unroll
    for (int p = 0; p < 4; ++p)
        hlv[p] = *(const bf16x8*)(Ls + (p * 16 + r0) * 136 + g * 8);

    for (int b = 0; b < B_SEQ; ++b) {
        floatx4 h0 = *(const floatx4*)(hpbs + b * 128 + g * 8);
        floatx4 h4 = *(const floatx4*)(hpbs + b * 128 + g * 8 + 4);
        size_t rowbase = (size_t)b * NLBL * 1024;
#pragma unroll
        for (int p = 0; p < 4; ++p) {
            int n = n0 + p * 16 + r0;
            if (n >= NLBL) continue;
            bf16x8 o;
            o[0] = (bf16)fmaxf((float)hlv[p][0] + h0.x, 0.f);
            o[1] = (bf16)fmaxf((float)hlv[p][1] + h0.y, 0.f);
            o[2] = (bf16)fmaxf((float)hlv[p][2] + h0.z, 0.f);
            o[3] = (bf16)fmaxf((float)hlv[p][3] + h0.w, 0.f);
            o[4] = (bf16)fmaxf((float)hlv[p][4] + h4.x, 0.f);
            o[5] = (bf16)fmaxf((float)hlv[p][5] + h4.y, 0.f);
            o[6] = (bf16)fmaxf((float)hlv[p][6] + h4.z, 0.f);
            o[7] = (bf16)fmaxf((float)hlv[p][7] + h4.w, 0.f);
            *(bf16x8*)(h1 + rowbase + (size_t)n * 1024 + d0 + g * 8) = o;
        }
    }
}

// ============ K4: h1 @ W2.T — R15 continuous-staging counted-vmcnt pipeline ====
// 256x256 tile, 8 waves, BK=64, 2-dbuf. NEW wave map: each wave owns two
// 64-row strips (one per A-half: wr*64 and 128+wr*64) x two 32-col strips
// (one per B-half: wc*32 and 128+wc*32). Per-phase reads then touch exactly
// one half-region: A-h0,B-h0 die at ph1, B-h1 at ph2, A-h1 at ph3 -> one
// HALF-TILE (2 loads/thread) staged EVERY phase into the region freed one
// phase earlier, 2 K-tiles ahead, same buffer being read:
//   ph1: stage A-h1(kt+1)->other buf | ph2: A-h0(kt+2)->cur | ph3: B-h0(kt+2)
//   | ph4: B-h1(kt+2).
// Region safety: each stage issues after the 2nd barrier of the phase where
// its region was last read (reads retire at lgkm before MFMA -> before that
// barrier). Landing: vmcnt(6)+barrier at each K-tile boundary => all but the
// 3 newest half-tiles landed collectively; every read is >=4th-newest at its
// guarding boundary (incl. prologue: 7 halves staged, vmcnt(6) = tile0
// complete; tail: vmcnt(0) at kt=14). Pipe NEVER drains in steady state.

__device__ __forceinline__ void stage_halfA(const bf16* __restrict__ src, bf16* dst,
                                            int m0, int roff, int kc, int t) {
#pragma unroll
    for (int i = 0; i < 2; ++i) {
        int s = t + i * 512;                // 0..1023
        int row = roff + (s >> 3);          // roff + 0..127
        int cg = (s & 7) ^ (row & 7);
        int grow = m0 + row;
        if (grow >= NROWS) grow = NROWS - 1;
        gload_lds16(src + (size_t)grow * 1024 + kc + cg * 8, dst + row * 64 + (s & 7) * 8);
    }
}

__device__ __forceinline__ void stage_halfB(const bf16* __restrict__ src, bf16* dst,
                                            int n0, int roff, int kc, int t) {
#pragma unroll
    for (int i = 0; i < 2; ++i) {
        int s = t + i * 512;
        int row = roff + (s >> 3);
        int cg = (s & 7) ^ (row & 7);
        gload_lds16(src + (size_t)(n0 + row) * 1024 + kc + cg * 8, dst + row * 64 + (s & 7) * 8);
    }
}

__global__ __launch_bounds__(512, 2)
void gemm_h2(const bf16* __restrict__ h1, const bf16* __restrict__ W2b,
             const float* __restrict__ b2, const float* __restrict__ W3,
             float* __restrict__ out) {
    __shared__ bf16 As[32768];              // 2 x [256][64]
    __shared__ bf16 Bs[32768];              // 2 x [256][64]
    const int t = threadIdx.x;

    // bijective XCD swizzle over nwg=1252 (q=156, r=4; m204 formula)
    int orig = blockIdx.x;
    int xcd = orig & 7, idx = orig >> 3;
    int wg = (xcd < 4 ? xcd * 157 : 628 + (xcd - 4) * 156) + idx;
    const int mt = wg >> 2, nt = wg & 3;    // 313 m-tiles x 4 n-tiles
    const int m0 = mt * 256, n0 = nt * 256;

    const int wave = t >> 6, lane = t & 63;
    const int wr = wave >> 2, wc = wave & 3;
    const int lm = lane & 15, quad = lane >> 4;
    const int swz = lm & 7;
    const int sl0 = (quad ^ swz) << 3;
    const int sl1 = ((4 + quad) ^ swz) << 3;

    floatx4 acc[8][4] = {};
    bf16x8 a[4][2], b0f[2][2], b1f[2][2];

    // ---- prologue: tile0 fully + tile1 {A-h0,B-h0,B-h1}; vmcnt(6) => tile0 landed
    stage_halfA(h1, As, m0, 0, 0, t);
    stage_halfB(W2b, Bs, n0, 0, 0, t);
    stage_halfB(W2b, Bs, n0, 128, 0, t);
    stage_halfA(h1, As, m0, 128, 0, t);
    stage_halfA(h1, As + 16384, m0, 0, 64, t);
    stage_halfB(W2b, Bs + 16384, n0, 0, 64, t);
    stage_halfB(W2b, Bs + 16384, n0, 128, 64, t);
    asm volatile("s_waitcnt vmcnt(6)" ::: "memory");
    barx();

    for (int kt = 0; kt < 16; ++kt) {
        const int db = kt & 1;
        const bf16* Ad = As + db * 16384;
        const bf16* Bd = Bs + db * 16384;
        bf16* Aoth = As + (db ^ 1) * 16384; // A-h1(kt+1) target
        bf16* Acur = As + db * 16384;       // tile kt+2 targets (same parity)
        bf16* Bcur = Bs + db * 16384;
        const int kc1 = (kt + 1) * 64;
        const int kc2 = (kt + 2) * 64;
        const bool p1 = (kt < 15), p2 = (kt < 14);

        // ---- ph1: read a-strip0 (A-h0) + b-cstrip0 (B-h0); stage A-h1(kt+1) ----
#pragma unroll
        for (int mi = 0; mi < 4; ++mi) {
            const bf16* rp = Ad + (wr * 64 + mi * 16 + lm) * 64;
            a[mi][0] = *(const bf16x8*)(rp + sl0);
            a[mi][1] = *(const bf16x8*)(rp + sl1);
        }
#pragma unroll
        for (int ni = 0; ni < 2; ++ni) {
            const bf16* rp = Bd + (wc * 32 + ni * 16 + lm) * 64;
            b0f[ni][0] = *(const bf16x8*)(rp + sl0);
            b0f[ni][1] = *(const bf16x8*)(rp + sl1);
        }
        if (p1) stage_halfA(h1, Aoth, m0, 128, kc1, t);
        barx();
        __builtin_amdgcn_s_setprio(1);
#pragma unroll
        for (int ks = 0; ks < 2; ++ks)
#pragma unroll
            for (int mi = 0; mi < 4; ++mi)
#pragma unroll
                for (int ni = 0; ni < 2; ++ni)
                    acc[mi][ni] = __builtin_amdgcn_mfma_f32_16x16x32_bf16(a[mi][ks], b0f[ni][ks], acc[mi][ni], 0, 0, 0);
        __builtin_amdgcn_s_setprio(0);
        barx();

        // ---- ph2: read b-cstrip1 (B-h1); stage A-h0(kt+2) [A-h0 freed ph1] ----
#pragma unroll
        for (int ni = 0; ni < 2; ++ni) {
            const bf16* rp = Bd + (128 + wc * 32 + ni * 16 + lm) * 64;
            b1f[ni][0] = *(const bf16x8*)(rp + sl0);
            b1f[ni][1] = *(const bf16x8*)(rp + sl1);
        }
        if (p2) stage_halfA(h1, Acur, m0, 0, kc2, t);
        barx();
        __builtin_amdgcn_s_setprio(1);
#pragma unroll
        for (int ks = 0; ks < 2; ++ks)
#pragma unroll
            for (int mi = 0; mi < 4; ++mi)
#pragma unroll
                for (int ni = 0; ni < 2; ++ni)
                    acc[mi][2 + ni] = __builtin_amdgcn_mfma_f32_16x16x32_bf16(a[mi][ks], b1f[ni][ks], acc[mi][2 + ni], 0, 0, 0);
        __builtin_amdgcn_s_setprio(0);
        barx();

        // ---- ph3: read a-strip1 (A-h1); stage B-h0(kt+2) [B-h0 freed ph1] ----
#pragma unroll
        for (int mi = 0; mi < 4; ++mi) {
            const bf16* rp = Ad + (128 + wr * 64 + mi * 16 + lm) * 64;
            a[mi][0] = *(const bf16x8*)(rp + sl0);
            a[mi][1] = *(const bf16x8*)(rp + sl1);
        }
        if (p2) stage_halfB(W2b, Bcur, n0, 0, kc2, t);
        barx();
        __builtin_amdgcn_s_setprio(1);
#pragma unroll
        for (int ks = 0; ks < 2; ++ks)
#pragma unroll
            for (int mi = 0; mi < 4; ++mi)
#pragma unroll
                for (int ni = 0; ni < 2; ++ni)
                    acc[4 + mi][ni] = __builtin_amdgcn_mfma_f32_16x16x32_bf16(a[mi][ks], b0f[ni][ks], acc[4 + mi][ni], 0, 0, 0);
        __builtin_amdgcn_s_setprio(0);
        barx();

        // ---- ph4: stage B-h1(kt+2) [freed ph2]; MFMA; boundary counted wait ----
        if (p2) stage_halfB(W2b, Bcur, n0, 128, kc2, t);
        __builtin_amdgcn_s_setprio(1);
#pragma unroll
        for (int ks = 0; ks < 2; ++ks)
#pragma unroll
            for (int mi = 0; mi < 4; ++mi)
#pragma unroll
                for (int ni = 0; ni < 2; ++ni)
                    acc[4 + mi][2 + ni] = __builtin_amdgcn_mfma_f32_16x16x32_bf16(a[mi][ks], b1f[ni][ks], acc[4 + mi][2 + ni], 0, 0, 0);
        __builtin_amdgcn_s_setprio(0);
        if (kt <= 13) {
            asm volatile("s_waitcnt vmcnt(6)" ::: "memory");
            barx();
        } else if (kt == 14) {
            asm volatile("s_waitcnt vmcnt(0)" ::: "memory");
            barx();
        }
        // kt == 15: fall through to epilogue (register-only)
    }

    // fused epilogue: out[row] += sum_col relu(acc + b2) * W3  (strip layout)
    float w3v[4], b2v[4];
#pragma unroll
    for (int ni = 0; ni < 4; ++ni) {
        int col = n0 + ((ni & 2) ? 128 : 0) + wc * 32 + (ni & 1) * 16 + lm;
        w3v[ni] = W3[col];
        b2v[ni] = b2[col];
    }
#pragma unroll
    for (int mi = 0; mi < 8; ++mi) {
#pragma unroll
        for (int r = 0; r < 4; ++r) {
            float sacc = 0.f;
#pragma unroll
            for (int ni = 0; ni < 4; ++ni)
                sacc += fmaxf(acc[mi][ni][r] + b2v[ni], 0.f) * w3v[ni];
            sacc += __shfl_xor(sacc, 1, 64);
            sacc += __shfl_xor(sacc, 2, 64);
            sacc += __shfl_xor(sacc, 4, 64);
            sacc += __shfl_xor(sacc, 8, 64);
            int row = m0 + ((mi >= 4) ? 128 : 0) + wr * 64 + (mi & 3) * 16 + quad * 4 + r;
            if (lm == 0 && row < NROWS)
                atomicAdd(out + row, sacc);
        }
    }
}

// ---------------- launch ----------------

extern "C" void kernel_launch(void* const* d_in, const int* in_sizes, int n_in,
                              void* d_out, int out_size, void* d_ws, size_t ws_size,
                              hipStream_t stream) {
    const float* seq   = (const float*)d_in[0];
    const float* label = (const float*)d_in[1];
    const float* Wp    = (const float*)d_in[2];
    const float* Wl    = (const float*)d_in[3];
    const float* W1    = (const float*)d_in[4];
    const float* b1    = (const float*)d_in[5];
    const float* W2    = (const float*)d_in[6];
    const float* b2    = (const float*)d_in[7];
    const float* W3    = (const float*)d_in[8];
    const float* b3    = (const float*)d_in[9];
    float* out = (float*)d_out;
    (void)n_in; (void)in_sizes; (void)out_size; (void)ws_size;

    size_t off = 0;
    auto alloc = [&](size_t bytes) {
        void* p = (char*)d_ws + off;
        off += (bytes + 255) & ~(size_t)255;
        return p;
    };
    bf16* label_b = (bf16*)alloc((size_t)NLBL * 1024 * 2);
    bf16* W2_b    = (bf16*)alloc((size_t)1024 * 1024 * 2);
    bf16* M_bf    = (bf16*)alloc((size_t)1024 * 1024 * 2);
    float* Pe     = (float*)alloc((size_t)B_SEQ * 1024 * 4);
    float* hpb    = (float*)alloc((size_t)B_SEQ * 1024 * 4);
    bf16* h1      = (bf16*)alloc((size_t)NROWS * 1024 * 2);

    prep_kernel<<<PSEG_END, 256, 0, stream>>>(label, label_b, W2, W2_b, W1, Wl,
                                              M_bf, seq, Wp, Pe, out, b3);
    hpb_kernel<<<256, 256, 0, stream>>>(Pe, W1, b1, hpb);
    hl_h1_kernel<<<dim3(8, 79), 256, 0, stream>>>(label_b, M_bf, hpb, h1);
    gemm_h2<<<1252, 512, 0, stream>>>(h1, W2_b, b2, W3, out);
}

// Round 8
// 323.208 us; speedup vs baseline: 1.0582x; 1.0582x over previous
//
#include <hip/hip_runtime.h>
#include <hip/hip_bf16.h>
#include <stdint.h>

typedef __bf16 bf16;
typedef __bf16 bf16x4 __attribute__((ext_vector_type(4)));
typedef __bf16 bf16x8 __attribute__((ext_vector_type(8)));
typedef float floatx4 __attribute__((ext_vector_type(4)));

#define B_SEQ 16
#define NLBL  5000
#define DLAT  1024
#define PDIM  1100
#define NROWS (B_SEQ * NLBL)   // 80000

// NOTE (R6): never use the builtin's immediate-offset arg — it mis-addresses.
// NOTE (R8): 32x32 MFMA frag reads 4-way bank-conflict under this LDS layout.
// NOTE (R11/R12/R13/R15 ALL FAILED, R14 NULL): K4 schedule is CONVERGED at the
// R10/R14 form (177us, 943TF, MfmaUtil 39.5%). Losses: clumped prefetch +15,
// in-loop A-gen +103, read-ahead +21, per-phase half-tile streaming w/
// vmcnt(6) +25. Do NOT perturb K4's barrier/stage/read placement again.
// NOTE (R16): K3 grid was dim3(8,79) with d-tile = blockIdx.x -> the 8
// d-chunk writers of the same h1 rows landed on 8 DIFFERENT XCDs (bid%8=x),
// fragmenting every 2KB row into 8x256B streams across 8 L2s (DRAM write
// thrash). Remap: bid&7 = n-tile&7 pins all 8 d-chunks of a row-set to one
// XCD; its L2 writes back dense row segments.
// NOTE (R17): R16 bench never ran (container acquisition failed twice —
// infra). Resubmitted unchanged; diff audited hang-free (uniform early
// return before any barrier; K4 byte-identical to verified R14).
__device__ __forceinline__ void gload_lds16(const bf16* g, bf16* l) {
    __builtin_amdgcn_global_load_lds(
        (const __attribute__((address_space(1))) void*)g,
        (__attribute__((address_space(3))) void*)l, 16, 0, 0);
}

__device__ __forceinline__ bf16x8 cvt8(const float* s) {
    floatx4 a = *(const floatx4*)s;
    floatx4 b = *(const floatx4*)(s + 4);
    bf16x8 o;
    o[0] = (bf16)a.x; o[1] = (bf16)a.y; o[2] = (bf16)a.z; o[3] = (bf16)a.w;
    o[4] = (bf16)b.x; o[5] = (bf16)b.y; o[6] = (bf16)b.z; o[7] = (bf16)b.w;
    return o;
}

__device__ __forceinline__ void barx() {
    asm volatile("" ::: "memory");
    __builtin_amdgcn_s_barrier();
    asm volatile("" ::: "memory");
}

// ============ K1: prep ============
#define PSEG_M    256
#define PSEG_LAB  2756
#define PSEG_W2   3268
#define PSEG_PE   3524
#define PSEG_END  3837

__global__ __launch_bounds__(256)
void prep_kernel(const float* __restrict__ label, bf16* __restrict__ label_b,
                 const float* __restrict__ W2, bf16* __restrict__ W2_b,
                 const float* __restrict__ W1, const float* __restrict__ Wl,
                 bf16* __restrict__ M_bf,
                 const float* __restrict__ seq, const float* __restrict__ Wp,
                 float* __restrict__ Pe,
                 float* __restrict__ out, const float* __restrict__ b3) {
    __shared__ bf16 MAs[64 * 72];
    __shared__ bf16 MBs[64 * 72];
    const int blk = blockIdx.x;
    const int t = threadIdx.x;

    if (blk < PSEG_M) {                     // M-product, 64x64 tiles, 16x16 grid
        const int m0 = (blk >> 4) * 64;
        const int n0g = (blk & 15) * 64;
        const int wave = t >> 6, lane = t & 63;
        const int wm = (wave & 1) * 32, wn = (wave >> 1) * 32;
        const int lm = lane & 15, quad = lane >> 4;
        const int a_r = t >> 2, a_c = (t & 3) * 16;
        const int b_kr = t >> 4, b_l = (t & 15) * 4;
        floatx4 acc[2][2] = {};

        for (int k0 = 0; k0 < 1024; k0 += 64) {
            const float* ap = W1 + (size_t)(m0 + a_r) * 2048 + 1024 + k0 + a_c;
            *(bf16x8*)(MAs + a_r * 72 + a_c) = cvt8(ap);
            *(bf16x8*)(MAs + a_r * 72 + a_c + 8) = cvt8(ap + 8);
#pragma unroll
            for (int ps = 0; ps < 4; ++ps) {
                int kr = b_kr + ps * 16;
                floatx4 v = *(const floatx4*)(Wl + (size_t)(k0 + kr) * 1024 + n0g + b_l);
                MBs[(b_l + 0) * 72 + kr] = (bf16)v.x;
                MBs[(b_l + 1) * 72 + kr] = (bf16)v.y;
                MBs[(b_l + 2) * 72 + kr] = (bf16)v.z;
                MBs[(b_l + 3) * 72 + kr] = (bf16)v.w;
            }
            __syncthreads();
#pragma unroll
            for (int ks = 0; ks < 2; ++ks) {
                bf16x8 af[2], bg[2];
#pragma unroll
                for (int mi = 0; mi < 2; ++mi)
                    af[mi] = *(const bf16x8*)(MAs + (wm + mi * 16 + lm) * 72 + ks * 32 + quad * 8);
#pragma unroll
                for (int ni = 0; ni < 2; ++ni)
                    bg[ni] = *(const bf16x8*)(MBs + (wn + ni * 16 + lm) * 72 + ks * 32 + quad * 8);
#pragma unroll
                for (int mi = 0; mi < 2; ++mi)
#pragma unroll
                    for (int ni = 0; ni < 2; ++ni)
                        acc[mi][ni] = __builtin_amdgcn_mfma_f32_16x16x32_bf16(af[mi], bg[ni], acc[mi][ni], 0, 0, 0);
            }
            __syncthreads();
        }
#pragma unroll
        for (int mi = 0; mi < 2; ++mi)
#pragma unroll
            for (int r = 0; r < 4; ++r)
#pragma unroll
                for (int ni = 0; ni < 2; ++ni)
                    M_bf[(size_t)(m0 + wm + mi * 16 + quad * 4 + r) * 1024 + n0g + wn + ni * 16 + lm] =
                        (bf16)acc[mi][ni][r];
    } else if (blk < PSEG_LAB) {            // label convert
        int i = (blk - PSEG_M) * 256 + t;
        ((bf16x8*)label_b)[i] = cvt8(label + (size_t)i * 8);
    } else if (blk < PSEG_W2) {             // W2 convert
        int i = (blk - PSEG_LAB) * 256 + t;
        ((bf16x8*)W2_b)[i] = cvt8(W2 + (size_t)i * 8);
    } else if (blk < PSEG_PE) {             // Pe, wave per d
        int w = (blk - PSEG_W2) * 4 + (t >> 6);
        int l = t & 63;
        floatx4 wv[5];
#pragma unroll
        for (int k = 0; k < 5; ++k) {
            int g = l + 64 * k;
            wv[k] = (g < 275) ? *(const floatx4*)(Wp + (size_t)w * PDIM + g * 4)
                              : floatx4{0.f, 0.f, 0.f, 0.f};
        }
        for (int b = 0; b < B_SEQ; ++b) {
            float acc = 0.f;
#pragma unroll
            for (int k = 0; k < 5; ++k) {
                int g = l + 64 * k;
                if (g < 275) {
                    floatx4 sv = *(const floatx4*)(seq + (size_t)b * PDIM + g * 4);
                    acc += wv[k].x * sv.x + wv[k].y * sv.y + wv[k].z * sv.z + wv[k].w * sv.w;
                }
            }
#pragma unroll
            for (int off = 32; off; off >>= 1) acc += __shfl_xor(acc, off, 64);
            if (l == 0) Pe[b * DLAT + w] = acc;
        }
    } else {                                // out init
        int i = (blk - PSEG_PE) * 256 + t;
        if (i < NROWS) out[i] = b3[0];
    }
}

// ============ K2: hpb[b,o] = b1[o] + Pe[b,:].W1[o,0:1024]  (f32 exact) ============

__global__ __launch_bounds__(256)
void hpb_kernel(const float* __restrict__ Pe, const float* __restrict__ W1,
                const float* __restrict__ b1, float* __restrict__ hpb) {
    int w = blockIdx.x * 4 + (threadIdx.x >> 6);
    int l = threadIdx.x & 63;
    floatx4 wv[4];
#pragma unroll
    for (int k = 0; k < 4; ++k)
        wv[k] = *(const floatx4*)(W1 + (size_t)w * 2048 + (l + 64 * k) * 4);
    for (int b = 0; b < B_SEQ; ++b) {
        float acc = 0.f;
#pragma unroll
        for (int k = 0; k < 4; ++k) {
            floatx4 pv = *(const floatx4*)(Pe + (size_t)b * DLAT + (l + 64 * k) * 4);
            acc += wv[k].x * pv.x + wv[k].y * pv.y + wv[k].z * pv.z + wv[k].w * pv.w;
        }
#pragma unroll
        for (int off = 32; off; off >>= 1) acc += __shfl_xor(acc, off, 64);
        if (l == 0) hpb[b * DLAT + w] = acc + b1[w];
    }
}

// ============ K3: hl GEMM (label @ M.T) with coalesced h1 epilogue ============
// R16: 1-D grid 640, XCD-pinned decode: ylo=bid&7, x=(bid>>3)&7, yhi=bid>>6,
// y = ylo + 8*yhi (n-tile), d0 = x*128. All 8 d-chunk writers of one row-set
// share XCD (bid&7 = y&7) -> dense per-L2 row write-back. Guard y>=79.

__global__ __launch_bounds__(256)
void hl_h1_kernel(const bf16* __restrict__ A, const bf16* __restrict__ Bt,
                  const float* __restrict__ hpb, bf16* __restrict__ h1) {
    __shared__ __align__(16) char smem[25600];
    bf16* As = (bf16*)smem;                 // 64 x 64 = 8 KB (K-loop)
    bf16* Bs = (bf16*)(smem + 8192);        // 128 x 64 = 16 KB (K-loop)
    bf16* Ls = (bf16*)smem;                 // 64*136*2 = 17408 B (epilogue)
    float* hpbs = (float*)(smem + 17408);   // 16*128*4 = 8192 B (epilogue)

    const int bid = blockIdx.x;
    const int ylo = bid & 7;
    const int x = (bid >> 3) & 7;
    const int yhi = bid >> 6;
    const int y = ylo + 8 * yhi;            // n-tile 0..79
    if (y >= 79) return;                    // uniform early exit (no syncs yet)

    const int t = threadIdx.x;
    const int d0 = x * 128;                 // d-tile (8)
    const int n0 = y * 64;                  // n-tile (79, last partial)
    const int wave = t >> 6, lane = t & 63;
    const int wm = (wave & 1) * 32;         // n offset within 64
    const int wn = (wave >> 1) * 64;        // d offset within 128
    const int lm = lane & 15, quad = lane >> 4;
    const int sw = lm & 7;
    const int srow = t >> 3;                // 0..31
    const int scg0 = t & 7;
    const int sbase = (t & 192) * 8;

    floatx4 acc[2][4] = {};

    for (int k0 = 0; k0 < 1024; k0 += 64) {
#pragma unroll
        for (int p = 0; p < 2; ++p) {       // A: 64 label rows
            int row = p * 32 + srow;
            int cg = scg0 ^ (row & 7);
            int grow = n0 + row; if (grow >= NLBL) grow = NLBL - 1;
            gload_lds16(A + (size_t)grow * 1024 + k0 + cg * 8, As + p * 2048 + sbase);
        }
#pragma unroll
        for (int p = 0; p < 4; ++p) {       // B: 128 M_bf rows (d)
            int row = p * 32 + srow;
            int cg = scg0 ^ (row & 7);
            gload_lds16(Bt + (size_t)(d0 + row) * 1024 + k0 + cg * 8, Bs + p * 2048 + sbase);
        }
        __syncthreads();
#pragma unroll
        for (int k = 0; k < 64; k += 32) {
            bf16x8 af[2], bg[4];
            int ko = (((k >> 3) + quad) ^ sw) * 8;
#pragma unroll
            for (int mi = 0; mi < 2; ++mi)
                af[mi] = *(const bf16x8*)(As + (wm + mi * 16 + lm) * 64 + ko);
#pragma unroll
            for (int ni = 0; ni < 4; ++ni)
                bg[ni] = *(const bf16x8*)(Bs + (wn + ni * 16 + lm) * 64 + ko);
#pragma unroll
            for (int mi = 0; mi < 2; ++mi)
#pragma unroll
                for (int ni = 0; ni < 4; ++ni)
                    acc[mi][ni] = __builtin_amdgcn_mfma_f32_16x16x32_bf16(af[mi], bg[ni], acc[mi][ni], 0, 0, 0);
        }
        __syncthreads();
    }

    // acc -> Ls (bf16 hl tile), stage hpb slice
#pragma unroll
    for (int mi = 0; mi < 2; ++mi)
#pragma unroll
        for (int r = 0; r < 4; ++r)
#pragma unroll
            for (int ni = 0; ni < 4; ++ni)
                Ls[(wm + mi * 16 + quad * 4 + r) * 136 + wn + ni * 16 + lm] =
                    (bf16)acc[mi][ni][r];
    {
        int dl = (t & 31) * 4;
        int b = t >> 5;                     // 0..7
        *(floatx4*)(hpbs + b * 128 + dl) =
            *(const floatx4*)(hpb + (size_t)b * DLAT + d0 + dl);
        *(floatx4*)(hpbs + (b + 8) * 128 + dl) =
            *(const floatx4*)(hpb + (size_t)(b + 8) * DLAT + d0 + dl);
    }
    __syncthreads();

    const int g = t & 15;                   // d-granule (16B)
    const int r0 = t >> 4;                  // 0..15 base row
    bf16x8 hlv[4];
#pragma unroll
    for (int p = 0; p < 4; ++p)
        hlv[p] = *(const bf16x8*)(Ls + (p * 16 + r0) * 136 + g * 8);

    for (int b = 0; b < B_SEQ; ++b) {
        floatx4 h0 = *(const floatx4*)(hpbs + b * 128 + g * 8);
        floatx4 h4 = *(const floatx4*)(hpbs + b * 128 + g * 8 + 4);
        size_t rowbase = (size_t)b * NLBL * 1024;
#pragma unroll
        for (int p = 0; p < 4; ++p) {
            int n = n0 + p * 16 + r0;
            if (n >= NLBL) continue;
            bf16x8 o;
            o[0] = (bf16)fmaxf((float)hlv[p][0] + h0.x, 0.f);
            o[1] = (bf16)fmaxf((float)hlv[p][1] + h0.y, 0.f);
            o[2] = (bf16)fmaxf((float)hlv[p][2] + h0.z, 0.f);
            o[3] = (bf16)fmaxf((float)hlv[p][3] + h0.w, 0.f);
            o[4] = (bf16)fmaxf((float)hlv[p][4] + h4.x, 0.f);
            o[5] = (bf16)fmaxf((float)hlv[p][5] + h4.y, 0.f);
            o[6] = (bf16)fmaxf((float)hlv[p][6] + h4.z, 0.f);
            o[7] = (bf16)fmaxf((float)hlv[p][7] + h4.w, 0.f);
            *(bf16x8*)(h1 + rowbase + (size_t)n * 1024 + d0 + g * 8) = o;
        }
    }
}

// ============ K4: main GEMM h1 @ W2.T — R14 schedule (VERIFIED BEST, frozen) ====
// 512 thr = 8 waves (2M x 4N), BK=64, 2-dbuf, stage A in ph1 / B in ph2,
// single vmcnt(0) at end of ph4, ks-outer MFMA. 176.8us / 943TF.

__device__ __forceinline__ void stage_A256(const bf16* __restrict__ src, bf16* dst,
                                           int m0, int kc, int t) {
#pragma unroll
    for (int i = 0; i < 4; ++i) {
        int s = t + i * 512;                // 0..2047
        int row = s >> 3;                   // 0..255
        int cg = (s & 7) ^ (row & 7);
        int grow = m0 + row;
        if (grow >= NROWS) grow = NROWS - 1;    // last m-tile is half-valid
        gload_lds16(src + (size_t)grow * 1024 + kc + cg * 8, dst + s * 8);
    }
}

__device__ __forceinline__ void stage_B256(const bf16* __restrict__ src, bf16* dst,
                                           int n0, int kc, int t) {
#pragma unroll
    for (int i = 0; i < 4; ++i) {
        int s = t + i * 512;
        int row = s >> 3;
        int cg = (s & 7) ^ (row & 7);
        gload_lds16(src + (size_t)(n0 + row) * 1024 + kc + cg * 8, dst + s * 8);
    }
}

__global__ __launch_bounds__(512, 2)
void gemm_h2(const bf16* __restrict__ h1, const bf16* __restrict__ W2b,
             const float* __restrict__ b2, const float* __restrict__ W3,
             float* __restrict__ out) {
    __shared__ bf16 As[32768];              // 2 x [256][64]
    __shared__ bf16 Bs[32768];              // 2 x [256][64]
    const int t = threadIdx.x;

    // bijective XCD swizzle over nwg=1252 (q=156, r=4; m204 formula)
    int orig = blockIdx.x;
    int xcd = orig & 7, idx = orig >> 3;
    int wg = (xcd < 4 ? xcd * 157 : 628 + (xcd - 4) * 156) + idx;
    const int mt = wg >> 2, nt = wg & 3;    // 313 m-tiles x 4 n-tiles
    const int m0 = mt * 256, n0 = nt * 256;

    const int wave = t >> 6, lane = t & 63;
    const int wr = wave >> 2, wc = wave & 3;
    const int wrow = wr * 128, wcol = wc * 64;
    const int lm = lane & 15, quad = lane >> 4;
    const int swz = lm & 7;

    floatx4 acc[8][4] = {};

    // prologue: stage K-tile 0 into dbuf 0
    stage_A256(h1, As, m0, 0, t);
    stage_B256(W2b, Bs, n0, 0, t);
    asm volatile("s_waitcnt vmcnt(0)" ::: "memory");
    barx();

    for (int kt = 0; kt < 16; ++kt) {
        const int db = kt & 1;
        const bf16* Ad = As + db * 16384;
        const bf16* Bd = Bs + db * 16384;
        bf16* An = As + (db ^ 1) * 16384;
        bf16* Bn = Bs + (db ^ 1) * 16384;
        const bool pf = (kt < 15);
        const int kc = (kt + 1) * 64;

        bf16x8 a[4][2], blo[2][2], bhi[2][2];

        // ---- phase 1: frags A(mh0)+B(nh0) [12 ds_read_b128]; stage next A ----
#pragma unroll
        for (int mi = 0; mi < 4; ++mi) {
            const bf16* rp = Ad + (wrow + mi * 16 + lm) * 64;
            a[mi][0] = *(const bf16x8*)(rp + ((quad ^ swz) << 3));
            a[mi][1] = *(const bf16x8*)(rp + (((4 + quad) ^ swz) << 3));
        }
#pragma unroll
        for (int ni = 0; ni < 2; ++ni) {
            const bf16* rp = Bd + (wcol + ni * 16 + lm) * 64;
            blo[ni][0] = *(const bf16x8*)(rp + ((quad ^ swz) << 3));
            blo[ni][1] = *(const bf16x8*)(rp + (((4 + quad) ^ swz) << 3));
        }
        if (pf) stage_A256(h1, An, m0, kc, t);
        barx();
        __builtin_amdgcn_s_setprio(1);
#pragma unroll
        for (int ks = 0; ks < 2; ++ks)
#pragma unroll
            for (int mi = 0; mi < 4; ++mi)
#pragma unroll
                for (int ni = 0; ni < 2; ++ni)
                    acc[mi][ni] = __builtin_amdgcn_mfma_f32_16x16x32_bf16(a[mi][ks], blo[ni][ks], acc[mi][ni], 0, 0, 0);
        __builtin_amdgcn_s_setprio(0);
        barx();

        // ---- phase 2: frags B(nh1) [4 ds_read_b128]; stage next B ----
#pragma unroll
        for (int ni = 0; ni < 2; ++ni) {
            const bf16* rp = Bd + (wcol + 32 + ni * 16 + lm) * 64;
            bhi[ni][0] = *(const bf16x8*)(rp + ((quad ^ swz) << 3));
            bhi[ni][1] = *(const bf16x8*)(rp + (((4 + quad) ^ swz) << 3));
        }
        if (pf) stage_B256(W2b, Bn, n0, kc, t);
        barx();
        __builtin_amdgcn_s_setprio(1);
#pragma unroll
        for (int ks = 0; ks < 2; ++ks)
#pragma unroll
            for (int mi = 0; mi < 4; ++mi)
#pragma unroll
                for (int ni = 0; ni < 2; ++ni)
                    acc[mi][2 + ni] = __builtin_amdgcn_mfma_f32_16x16x32_bf16(a[mi][ks], bhi[ni][ks], acc[mi][2 + ni], 0, 0, 0);
        __builtin_amdgcn_s_setprio(0);
        barx();

        // ---- phase 3: frags A(mh1) [8 ds_read_b128] ----
#pragma unroll
        for (int mi = 0; mi < 4; ++mi) {
            const bf16* rp = Ad + (wrow + 64 + mi * 16 + lm) * 64;
            a[mi][0] = *(const bf16x8*)(rp + ((quad ^ swz) << 3));
            a[mi][1] = *(const bf16x8*)(rp + (((4 + quad) ^ swz) << 3));
        }
        barx();
        __builtin_amdgcn_s_setprio(1);
#pragma unroll
        for (int ks = 0; ks < 2; ++ks)
#pragma unroll
            for (int mi = 0; mi < 4; ++mi)
#pragma unroll
                for (int ni = 0; ni < 2; ++ni)
                    acc[4 + mi][2 + ni] = __builtin_amdgcn_mfma_f32_16x16x32_bf16(a[mi][ks], bhi[ni][ks], acc[4 + mi][2 + ni], 0, 0, 0);
        __builtin_amdgcn_s_setprio(0);
        barx();

        // ---- phase 4: pure-reg MFMA; drain staging loads; buffer swap ----
        __builtin_amdgcn_s_setprio(1);
#pragma unroll
        for (int ks = 0; ks < 2; ++ks)
#pragma unroll
            for (int mi = 0; mi < 4; ++mi)
#pragma unroll
                for (int ni = 0; ni < 2; ++ni)
                    acc[4 + mi][ni] = __builtin_amdgcn_mfma_f32_16x16x32_bf16(a[mi][ks], blo[ni][ks], acc[4 + mi][ni], 0, 0, 0);
        __builtin_amdgcn_s_setprio(0);
        asm volatile("s_waitcnt vmcnt(0)" ::: "memory");
        barx();
    }

    // fused epilogue: out[row] += sum_col relu(acc + b2) * W3
    float w3v[4], b2v[4];
#pragma unroll
    for (int ni = 0; ni < 4; ++ni) {
        int col = n0 + wcol + ni * 16 + lm;
        w3v[ni] = W3[col];
        b2v[ni] = b2[col];
    }
#pragma unroll
    for (int mi = 0; mi < 8; ++mi) {
#pragma unroll
        for (int r = 0; r < 4; ++r) {
            float sacc = 0.f;
#pragma unroll
            for (int ni = 0; ni < 4; ++ni)
                sacc += fmaxf(acc[mi][ni][r] + b2v[ni], 0.f) * w3v[ni];
            sacc += __shfl_xor(sacc, 1, 64);
            sacc += __shfl_xor(sacc, 2, 64);
            sacc += __shfl_xor(sacc, 4, 64);
            sacc += __shfl_xor(sacc, 8, 64);
            int row = m0 + wrow + mi * 16 + quad * 4 + r;
            if (lm == 0 && row < NROWS)
                atomicAdd(out + row, sacc);
        }
    }
}

// ---------------- launch ----------------

extern "C" void kernel_launch(void* const* d_in, const int* in_sizes, int n_in,
                              void* d_out, int out_size, void* d_ws, size_t ws_size,
                              hipStream_t stream) {
    const float* seq   = (const float*)d_in[0];
    const float* label = (const float*)d_in[1];
    const float* Wp    = (const float*)d_in[2];
    const float* Wl    = (const float*)d_in[3];
    const float* W1    = (const float*)d_in[4];
    const float* b1    = (const float*)d_in[5];
    const float* W2    = (const float*)d_in[6];
    const float* b2    = (const float*)d_in[7];
    const float* W3    = (const float*)d_in[8];
    const float* b3    = (const float*)d_in[9];
    float* out = (float*)d_out;
    (void)n_in; (void)in_sizes; (void)out_size; (void)ws_size;

    size_t off = 0;
    auto alloc = [&](size_t bytes) {
        void* p = (char*)d_ws + off;
        off += (bytes + 255) & ~(size_t)255;
        return p;
    };
    bf16* label_b = (bf16*)alloc((size_t)NLBL * 1024 * 2);
    bf16* W2_b    = (bf16*)alloc((size_t)1024 * 1024 * 2);
    bf16* M_bf    = (bf16*)alloc((size_t)1024 * 1024 * 2);
    float* Pe     = (float*)alloc((size_t)B_SEQ * 1024 * 4);
    float* hpb    = (float*)alloc((size_t)B_SEQ * 1024 * 4);
    bf16* h1      = (bf16*)alloc((size_t)NROWS * 1024 * 2);

    prep_kernel<<<PSEG_END, 256, 0, stream>>>(label, label_b, W2, W2_b, W1, Wl,
                                              M_bf, seq, Wp, Pe, out, b3);
    hpb_kernel<<<256, 256, 0, stream>>>(Pe, W1, b1, hpb);
    hl_h1_kernel<<<640, 256, 0, stream>>>(label_b, M_bf, hpb, h1);
    gemm_h2<<<1252, 512, 0, stream>>>(h1, W2_b, b2, W3, out);
}